// Round 9
// baseline (210.102 us; speedup 1.0000x reference)
//
#include <hip/hip_runtime.h>

#define T_SEQ 4096
#define DIM   64
#define NQT   32     // T / 128
#define QTILE 256    // 256 q-rows per block (8 waves)
#define KTILE 128
#define NBH   32     // B*H
#define NQT2  16     // T / 256

typedef __attribute__((ext_vector_type(8)))  short bhalf8;
typedef __attribute__((ext_vector_type(16))) float floatx16;

#if __has_builtin(__builtin_amdgcn_exp2f)
#define EXP2F(x) __builtin_amdgcn_exp2f(x)
#else
#define EXP2F(x) exp2f(x)
#endif

// sigma: swap bits 2<->3 (kv permutation matching MFMA C->B register order)
__device__ __forceinline__ int sig23(int s) {
  return (s & ~12) | ((s & 4) << 1) | ((s & 8) >> 1);
}

// pack two fp32 -> two bf16 (round-half-up) in one v_perm_b32
__device__ __forceinline__ unsigned pk2bf(float a, float b) {
  unsigned ua = __builtin_bit_cast(unsigned, a) + 0x8000u;
  unsigned ub = __builtin_bit_cast(unsigned, b) + 0x8000u;
  return __builtin_amdgcn_perm(ub, ua, 0x07060302u);
}

// pack two fp32 -> two bf16 (RNE) in ONE instruction (no builtin on gfx950)
__device__ __forceinline__ unsigned cvtpk(float a, float b) {
  unsigned r;
  asm("v_cvt_pk_bf16_f32 %0, %1, %2" : "=v"(r) : "v"(a), "v"(b));
  return r;
}

union FragU { unsigned u[4]; bhalf8 v; };

__device__ __forceinline__ void gload_lds16(const void* g, void* l) {
#if __has_builtin(__builtin_amdgcn_global_load_lds)
  __builtin_amdgcn_global_load_lds(
      (const __attribute__((address_space(1))) unsigned*)g,
      (__attribute__((address_space(3))) unsigned*)l, 16, 0, 0);
#else
  *(uint4*)l = *(const uint4*)g;
#endif
}

// ---------------- prep: fp32 K/V -> bf16 swizzled tiles in ws ----------------
__global__ __launch_bounds__(256, 2) void fa_prep(
    const float* __restrict__ K, const float* __restrict__ V,
    unsigned short* __restrict__ Kb, unsigned short* __restrict__ Vb) {
  const int tid = threadIdx.x;
  const int bid = blockIdx.x;
  const int bh = bid >> 5, kt = bid & 31;
  __shared__ __align__(16) unsigned short SS[16384];  // Kl[0..8191], Vt[8192..16383]
  __shared__ __align__(16) float VS[128 * 68];        // fp32 V tile, padded stride 68
  unsigned short* Kl = SS;
  unsigned short* Vt = SS + 8192;
  const int base = bh * (T_SEQ * DIM) + kt * (KTILE * DIM);

  // K tile: row kv, 8 chunks of 8 bf16, chunk swizzle c' = c ^ (kv&7)
  {
    const float4* kp4 = reinterpret_cast<const float4*>(K + base);
    float4 kx[8];
#pragma unroll
    for (int c = 0; c < 8; ++c) kx[c] = kp4[tid + 256 * c];
#pragma unroll
    for (int c = 0; c < 8; ++c) {
      int f4 = tid + 256 * c;
      int kv = f4 >> 4;
      int d0 = (f4 & 15) << 2;
      unsigned lo = pk2bf(kx[c].x, kx[c].y);
      unsigned hi = pk2bf(kx[c].z, kx[c].w);
      unsigned long long u64 = (unsigned long long)lo | ((unsigned long long)hi << 32);
      int idx = (kv << 6) | ((((d0 >> 3) ^ (kv & 7)) << 3) | (d0 & 7));
      *reinterpret_cast<unsigned long long*>(&Kl[idx]) = u64;
    }
  }
  // V tile: coalesced load, fp32 transpose staging in LDS
  {
    const float4* vp4 = reinterpret_cast<const float4*>(V + base);
#pragma unroll
    for (int c = 0; c < 8; ++c) {
      float4 x = vp4[tid + 256 * c];
      int f4 = tid + 256 * c;
      int kv = f4 >> 4;
      int d0 = (f4 & 15) << 2;
      *reinterpret_cast<float4*>(&VS[kv * 68 + d0]) = x;
    }
  }
  __syncthreads();
  // read columns from VS (sigma-permuted kv), pack into swizzled Vt slots
  {
    const int s0 = (tid & 63) << 1;        // slot pair (even)
    const int db = (tid >> 6) << 4;        // d base (16 per group)
    const int kva = sig23(s0);             // sigma on even slot (bit0 unaffected)
    const int kvb = kva + 1;
    float4 va[4], vb[4];
#pragma unroll
    for (int sg = 0; sg < 4; ++sg) {
      va[sg] = *reinterpret_cast<const float4*>(&VS[kva * 68 + db + 4 * sg]);
      vb[sg] = *reinterpret_cast<const float4*>(&VS[kvb * 68 + db + 4 * sg]);
    }
    const float* vaf = reinterpret_cast<const float*>(va);
    const float* vbf = reinterpret_cast<const float*>(vb);
#pragma unroll
    for (int j = 0; j < 16; ++j) {
      int d = db + j;
      unsigned u = pk2bf(vaf[j], vbf[j]);  // low = slot s0, high = s0+1
      int idx = (d << 7) | ((((s0 >> 3) ^ (d & 15)) << 3) | (s0 & 7));
      *reinterpret_cast<unsigned*>(&Vt[idx]) = u;
    }
  }
  __syncthreads();
  // linear dump to global (coalesced uint4)
  const uint4* S4 = reinterpret_cast<const uint4*>(SS);
  uint4* KbT = reinterpret_cast<uint4*>(Kb + (size_t)(bh * 32 + kt) * 8192);
  uint4* VbT = reinterpret_cast<uint4*>(Vb + (size_t)(bh * 32 + kt) * 8192);
#pragma unroll
  for (int i = 0; i < 4; ++i) KbT[tid + 256 * i] = S4[tid + 256 * i];
#pragma unroll
  for (int i = 0; i < 4; ++i) VbT[tid + 256 * i] = S4[1024 + tid + 256 * i];
}

// ---------------- main: ONE block per (bh, qt2) — 256 q-rows, full row ------
// v8b: QTILE=256 amortization (theory unchanged from v8: halve staging
// barrier-stalls per unit compute, 16896 -> 8704 stagings; grid 512 blocks =
// fully co-resident at 2 blocks/CU). DISCRIMINATING CHANGE vs v8: staging is
// plain reg->ds_write (2x uint4 loads from Kb/Vb + 4x ds_write_b128 per
// thread) instead of global_load_lds — v8 failed 2x with dead containers and
// gload_lds@512-thread-workgroup was its only never-validated mechanism.
// ds_write has no wave-uniform-base constraint. LDS layout byte-identical.
__global__ __launch_bounds__(512, 2) void fa_main2(
    const float* __restrict__ Q, const unsigned short* __restrict__ Kb,
    const unsigned short* __restrict__ Vb, float* __restrict__ O) {
  const int tid  = threadIdx.x;
  const int w    = tid >> 6;               // 0..7
  const int lane = tid & 63;
  const int n    = lane & 31;
  const int h    = lane >> 5;
  const int bid  = blockIdx.x;
  const int bh   = bid & (NBH - 1);
  const int qt   = (NQT2 - 1) - (bid >> 5);   // heaviest rows first, 0..15

  const int kend = 2 * qt + 2;             // kv tiles 0..2qt+1
  const int base = bh * (T_SEQ * DIM);

  __shared__ __align__(16) unsigned short Kl[KTILE * DIM];
  __shared__ __align__(16) unsigned short Vt[DIM * KTILE];

  const int qloc = w * 32 + n;             // 0..255
  const int qrow = qt * QTILE + qloc;
  const float cs = 0.125f * 1.44269504088896340736f;
  FragU qf[4];
  {
    const float* qp = Q + base + qrow * DIM + h * 8;
#pragma unroll
    for (int ks = 0; ks < 4; ++ks) {
      float4 a = *reinterpret_cast<const float4*>(qp + 16 * ks);
      float4 b = *reinterpret_cast<const float4*>(qp + 16 * ks + 4);
      qf[ks].u[0] = cvtpk(a.x * cs, a.y * cs);
      qf[ks].u[1] = cvtpk(a.z * cs, a.w * cs);
      qf[ks].u[2] = cvtpk(b.x * cs, b.y * cs);
      qf[ks].u[3] = cvtpk(b.z * cs, b.w * cs);
    }
  }

  floatx16 o0, o1, zf;
#pragma unroll
  for (int i = 0; i < 16; ++i) { o0[i] = 0.f; o1[i] = 0.f; zf[i] = 0.f; }
  float s_run = 0.f;

  const int sw = n & 15;
  uint4* const kl4 = reinterpret_cast<uint4*>(Kl);
  uint4* const vl4 = reinterpret_cast<uint4*>(Vt);

  for (int kt = 0; kt < kend; ++kt) {
    __syncthreads();
    {
      // tile = 8192 shorts = 1024 uint4; 512 threads x 2 each; coalesced
      const uint4* kb4 = reinterpret_cast<const uint4*>(Kb + (size_t)((bh << 5) + kt) * 8192);
      const uint4* vb4 = reinterpret_cast<const uint4*>(Vb + (size_t)((bh << 5) + kt) * 8192);
      uint4 ka = kb4[tid], kbx = kb4[tid + 512];
      uint4 va = vb4[tid], vbx = vb4[tid + 512];
      kl4[tid] = ka;  kl4[tid + 512] = kbx;
      vl4[tid] = va;  vl4[tid + 512] = vbx;
    }
    __syncthreads();

    // S^T = K * Q^T (zero-C init via loop-invariant zf)
    floatx16 st[4];
#pragma unroll
    for (int tt = 0; tt < 4; ++tt) {
      const bhalf8 kf0 = *reinterpret_cast<const bhalf8*>(
          &Kl[((32 * tt + n) << 6) | (((0 + h) ^ (n & 7)) << 3)]);
      const bhalf8 kf1 = *reinterpret_cast<const bhalf8*>(
          &Kl[((32 * tt + n) << 6) | (((2 + h) ^ (n & 7)) << 3)]);
      const bhalf8 kf2 = *reinterpret_cast<const bhalf8*>(
          &Kl[((32 * tt + n) << 6) | (((4 + h) ^ (n & 7)) << 3)]);
      const bhalf8 kf3 = *reinterpret_cast<const bhalf8*>(
          &Kl[((32 * tt + n) << 6) | (((6 + h) ^ (n & 7)) << 3)]);
      __builtin_amdgcn_s_setprio(1);
      floatx16 acc = __builtin_amdgcn_mfma_f32_32x32x16_bf16(kf0, qf[0].v, zf, 0, 0, 0);
      acc = __builtin_amdgcn_mfma_f32_32x32x16_bf16(kf1, qf[1].v, acc, 0, 0, 0);
      acc = __builtin_amdgcn_mfma_f32_32x32x16_bf16(kf2, qf[2].v, acc, 0, 0, 0);
      acc = __builtin_amdgcn_mfma_f32_32x32x16_bf16(kf3, qf[3].v, acc, 0, 0, 0);
      __builtin_amdgcn_s_setprio(0);
      st[tt] = acc;
    }

    if (kt >= kend - 2) {  // causal mask: only last two kv tiles can cross diag
      const int thr = (qt * QTILE + qloc) - (kt << 7);  // mask kvloc > thr
#pragma unroll
      for (int tt = 0; tt < 4; ++tt)
#pragma unroll
        for (int r = 0; r < 16; ++r) {
          int kvloc = 32 * tt + (r & 3) + 8 * (r >> 2) + 4 * h;
          st[tt][r] = (kvloc > thr) ? -__builtin_inff() : st[tt][r];
        }
    }

    // softmax numerator (no max shift): p = exp2(score)
    float psum = 0.f;
#pragma unroll
    for (int tt = 0; tt < 4; ++tt)
#pragma unroll
      for (int r = 0; r < 16; ++r) {
        float p = EXP2F(st[tt][r]);
        st[tt][r] = p;
        psum += p;
      }
    psum += __shfl_xor(psum, 32, 64);
    s_run += psum;

    // P -> bf16 B-fragments (cvtpk: 1 instr/pair) + PV
#pragma unroll
    for (int tt = 0; tt < 4; ++tt) {
      FragU b0, b1;
      b0.u[0] = cvtpk(st[tt][0],  st[tt][1]);
      b0.u[1] = cvtpk(st[tt][2],  st[tt][3]);
      b0.u[2] = cvtpk(st[tt][4],  st[tt][5]);
      b0.u[3] = cvtpk(st[tt][6],  st[tt][7]);
      b1.u[0] = cvtpk(st[tt][8],  st[tt][9]);
      b1.u[1] = cvtpk(st[tt][10], st[tt][11]);
      b1.u[2] = cvtpk(st[tt][12], st[tt][13]);
      b1.u[3] = cvtpk(st[tt][14], st[tt][15]);

      const bhalf8 v00 = *reinterpret_cast<const bhalf8*>(
          &Vt[(n << 7) | (((4 * tt + 0 + h) ^ sw) << 3)]);
      const bhalf8 v01 = *reinterpret_cast<const bhalf8*>(
          &Vt[(n << 7) | (((4 * tt + 2 + h) ^ sw) << 3)]);
      const bhalf8 v10 = *reinterpret_cast<const bhalf8*>(
          &Vt[((32 + n) << 7) | (((4 * tt + 0 + h) ^ sw) << 3)]);
      const bhalf8 v11 = *reinterpret_cast<const bhalf8*>(
          &Vt[((32 + n) << 7) | (((4 * tt + 2 + h) ^ sw) << 3)]);

      __builtin_amdgcn_s_setprio(1);
      o0 = __builtin_amdgcn_mfma_f32_32x32x16_bf16(v00, b0.v, o0, 0, 0, 0);
      o0 = __builtin_amdgcn_mfma_f32_32x32x16_bf16(v01, b1.v, o0, 0, 0, 0);
      o1 = __builtin_amdgcn_mfma_f32_32x32x16_bf16(v10, b0.v, o1, 0, 0, 0);
      o1 = __builtin_amdgcn_mfma_f32_32x32x16_bf16(v11, b1.v, o1, 0, 0, 0);
      __builtin_amdgcn_s_setprio(0);
    }
  }

  // epilogue: normalized fp32 O, written directly
  const float inv = 1.0f / s_run;
  float* op = O + base + qrow * DIM;
#pragma unroll
  for (int g = 0; g < 4; ++g) {
    float4 x, y;
    x.x = o0[4 * g] * inv;  x.y = o0[4 * g + 1] * inv;
    x.z = o0[4 * g + 2] * inv;  x.w = o0[4 * g + 3] * inv;
    y.x = o1[4 * g] * inv;  y.y = o1[4 * g + 1] * inv;
    y.z = o1[4 * g + 2] * inv;  y.w = o1[4 * g + 3] * inv;
    *reinterpret_cast<float4*>(op + 8 * g + 4 * h)      = x;
    *reinterpret_cast<float4*>(op + 32 + 8 * g + 4 * h) = y;
  }
}

// ---------------- fallback (monolithic, sigma-permuted V) --------------------
__global__ __launch_bounds__(256, 2) void fa_mono(
    const float* __restrict__ Q, const float* __restrict__ K,
    const float* __restrict__ V, float* __restrict__ O) {
  const int tid  = threadIdx.x;
  const int w    = tid >> 6;
  const int lane = tid & 63;
  const int n    = lane & 31;
  const int h    = lane >> 5;
  const int bid  = blockIdx.x;
  const int bh   = bid & (NBH - 1);
  const int qt   = (NQT - 1) - (bid >> 5);

  const int base = bh * (T_SEQ * DIM);
  __shared__ __align__(16) unsigned short Kl[KTILE * DIM];
  __shared__ __align__(16) unsigned short Vt[DIM * KTILE];

  const int qrow = qt * 128 + w * 32 + n;
  const float cs = 0.125f * 1.44269504088896340736f;
  FragU qf[4];
  {
    const float* qp = Q + base + qrow * DIM + h * 8;
#pragma unroll
    for (int ks = 0; ks < 4; ++ks) {
      float4 a = *reinterpret_cast<const float4*>(qp + 16 * ks);
      float4 b = *reinterpret_cast<const float4*>(qp + 16 * ks + 4);
      qf[ks].u[0] = pk2bf(a.x * cs, a.y * cs);
      qf[ks].u[1] = pk2bf(a.z * cs, a.w * cs);
      qf[ks].u[2] = pk2bf(b.x * cs, b.y * cs);
      qf[ks].u[3] = pk2bf(b.z * cs, b.w * cs);
    }
  }

  floatx16 o0, o1;
#pragma unroll
  for (int i = 0; i < 16; ++i) { o0[i] = 0.f; o1[i] = 0.f; }
  float s_run = 0.f;

  for (int kt = 0; kt <= qt; ++kt) {
    __syncthreads();
    {
      const float4* kp4 = reinterpret_cast<const float4*>(K + base + kt * (KTILE * DIM));
      float4 kx[8];
#pragma unroll
      for (int c = 0; c < 8; ++c) kx[c] = kp4[tid + 256 * c];
#pragma unroll
      for (int c = 0; c < 8; ++c) {
        int f4 = tid + 256 * c;
        int kv = f4 >> 4;
        int d0 = (f4 & 15) << 2;
        unsigned lo = pk2bf(kx[c].x, kx[c].y);
        unsigned hi = pk2bf(kx[c].z, kx[c].w);
        unsigned long long u64 = (unsigned long long)lo | ((unsigned long long)hi << 32);
        int idx = (kv << 6) | ((((d0 >> 3) ^ (kv & 7)) << 3) | (d0 & 7));
        *reinterpret_cast<unsigned long long*>(&Kl[idx]) = u64;
      }
      const int s0 = (tid & 63) << 1;
      const int db = (tid >> 6) << 4;
      const int kva = sig23(s0);
      const float* vr0 = V + base + kt * (KTILE * DIM) + kva * DIM + db;
      const float* vr1 = vr0 + DIM;
      float4 va[4], vb[4];
#pragma unroll
      for (int sg = 0; sg < 4; ++sg) {
        va[sg] = *reinterpret_cast<const float4*>(vr0 + 4 * sg);
        vb[sg] = *reinterpret_cast<const float4*>(vr1 + 4 * sg);
      }
      const float* vaf = reinterpret_cast<const float*>(va);
      const float* vbf = reinterpret_cast<const float*>(vb);
#pragma unroll
      for (int j = 0; j < 16; ++j) {
        int d = db + j;
        unsigned u = pk2bf(vaf[j], vbf[j]);
        int idx = (d << 7) | ((((s0 >> 3) ^ (d & 15)) << 3) | (s0 & 7));
        *reinterpret_cast<unsigned*>(&Vt[idx]) = u;
      }
    }
    __syncthreads();

    floatx16 st[4];
#pragma unroll
    for (int tt = 0; tt < 4; ++tt) {
      floatx16 acc;
#pragma unroll
      for (int i = 0; i < 16; ++i) acc[i] = 0.f;
#pragma unroll
      for (int ks = 0; ks < 4; ++ks) {
        const bhalf8 kfrag = *reinterpret_cast<const bhalf8*>(
            &Kl[((32 * tt + n) << 6) | (((2 * ks + h) ^ (n & 7)) << 3)]);
        acc = __builtin_amdgcn_mfma_f32_32x32x16_bf16(kfrag, qf[ks].v, acc, 0, 0, 0);
      }
      st[tt] = acc;
    }

    if (kt == qt) {
#pragma unroll
      for (int tt = 0; tt < 4; ++tt)
#pragma unroll
        for (int r = 0; r < 16; ++r) {
          int kvloc = 32 * tt + (r & 3) + 8 * (r >> 2) + 4 * h;
          st[tt][r] = (kvloc > 32 * w + n) ? -__builtin_inff() : st[tt][r];
        }
    }

    float psum = 0.f;
#pragma unroll
    for (int tt = 0; tt < 4; ++tt)
#pragma unroll
      for (int r = 0; r < 16; ++r) {
        float p = EXP2F(st[tt][r]);
        st[tt][r] = p;
        psum += p;
      }
    psum += __shfl_xor(psum, 32, 64);
    s_run += psum;

#pragma unroll
    for (int tt = 0; tt < 4; ++tt) {
      FragU b0, b1;
      b0.u[0] = pk2bf(st[tt][0],  st[tt][1]);
      b0.u[1] = pk2bf(st[tt][2],  st[tt][3]);
      b0.u[2] = pk2bf(st[tt][4],  st[tt][5]);
      b0.u[3] = pk2bf(st[tt][6],  st[tt][7]);
      b1.u[0] = pk2bf(st[tt][8],  st[tt][9]);
      b1.u[1] = pk2bf(st[tt][10], st[tt][11]);
      b1.u[2] = pk2bf(st[tt][12], st[tt][13]);
      b1.u[3] = pk2bf(st[tt][14], st[tt][15]);

      const int sw = n & 15;
      const bhalf8 v00 = *reinterpret_cast<const bhalf8*>(
          &Vt[(n << 7) | (((4 * tt + 0 + h) ^ sw) << 3)]);
      const bhalf8 v01 = *reinterpret_cast<const bhalf8*>(
          &Vt[(n << 7) | (((4 * tt + 2 + h) ^ sw) << 3)]);
      const bhalf8 v10 = *reinterpret_cast<const bhalf8*>(
          &Vt[((32 + n) << 7) | (((4 * tt + 0 + h) ^ sw) << 3)]);
      const bhalf8 v11 = *reinterpret_cast<const bhalf8*>(
          &Vt[((32 + n) << 7) | (((4 * tt + 2 + h) ^ sw) << 3)]);
      o0 = __builtin_amdgcn_mfma_f32_32x32x16_bf16(v00, b0.v, o0, 0, 0, 0);
      o0 = __builtin_amdgcn_mfma_f32_32x32x16_bf16(v01, b1.v, o0, 0, 0, 0);
      o1 = __builtin_amdgcn_mfma_f32_32x32x16_bf16(v10, b0.v, o1, 0, 0, 0);
      o1 = __builtin_amdgcn_mfma_f32_32x32x16_bf16(v11, b1.v, o1, 0, 0, 0);
    }
  }

  const float inv = 1.0f / s_run;
  float* op = O + base + qrow * DIM;
#pragma unroll
  for (int g = 0; g < 4; ++g) {
    float4 x, y;
    x.x = o0[4 * g] * inv;  x.y = o0[4 * g + 1] * inv;
    x.z = o0[4 * g + 2] * inv;  x.w = o0[4 * g + 3] * inv;
    y.x = o1[4 * g] * inv;  y.y = o1[4 * g + 1] * inv;
    y.z = o1[4 * g + 2] * inv;  y.w = o1[4 * g + 3] * inv;
    *reinterpret_cast<float4*>(op + 8 * g + 4 * h)      = x;
    *reinterpret_cast<float4*>(op + 32 + 8 * g + 4 * h) = y;
  }
}

extern "C" void kernel_launch(void* const* d_in, const int* in_sizes, int n_in,
                              void* d_out, int out_size, void* d_ws, size_t ws_size,
                              hipStream_t stream) {
  (void)in_sizes; (void)n_in; (void)out_size;
  const float* Q = (const float*)d_in[0];
  const float* K = (const float*)d_in[1];
  const float* V = (const float*)d_in[2];
  float* O = (float*)d_out;

  // ws layout (bytes): Kb[16MB] | Vb[16MB]
  const size_t OFF_KB = 0;
  const size_t OFF_VB = 16777216;
  const size_t NEED   = 33554432;

  if (ws_size >= NEED) {
    unsigned short* Kb = (unsigned short*)((char*)d_ws + OFF_KB);
    unsigned short* Vb = (unsigned short*)((char*)d_ws + OFF_VB);
    fa_prep<<<dim3(NBH * NQT), dim3(256), 0, stream>>>(K, V, Kb, Vb);
    fa_main2<<<dim3(NBH * NQT2), dim3(512), 0, stream>>>(Q, Kb, Vb, O);
  } else {
    fa_mono<<<dim3(NQT * NBH), dim3(256), 0, stream>>>(Q, K, V, O);
  }
}

// Round 10
// 209.739 us; speedup vs baseline: 1.0017x; 1.0017x over previous
//
#include <hip/hip_runtime.h>

#define T_SEQ 4096
#define DIM   64
#define NQT   32     // T / 128
#define QTILE 256    // 256 q-rows per block (8 waves)
#define KTILE 128
#define NBH   32     // B*H
#define NQT2  16     // T / 256
#define NPAIR 8      // diagonal pairs (qt, 15-qt)

typedef __attribute__((ext_vector_type(8)))  short bhalf8;
typedef __attribute__((ext_vector_type(16))) float floatx16;

#if __has_builtin(__builtin_amdgcn_exp2f)
#define EXP2F(x) __builtin_amdgcn_exp2f(x)
#else
#define EXP2F(x) exp2f(x)
#endif

// sigma: swap bits 2<->3 (kv permutation matching MFMA C->B register order)
__device__ __forceinline__ int sig23(int s) {
  return (s & ~12) | ((s & 4) << 1) | ((s & 8) >> 1);
}

// pack two fp32 -> two bf16 (round-half-up) in one v_perm_b32
__device__ __forceinline__ unsigned pk2bf(float a, float b) {
  unsigned ua = __builtin_bit_cast(unsigned, a) + 0x8000u;
  unsigned ub = __builtin_bit_cast(unsigned, b) + 0x8000u;
  return __builtin_amdgcn_perm(ub, ua, 0x07060302u);
}

// pack two fp32 -> two bf16 (RNE) in ONE instruction (no builtin on gfx950)
__device__ __forceinline__ unsigned cvtpk(float a, float b) {
  unsigned r;
  asm("v_cvt_pk_bf16_f32 %0, %1, %2" : "=v"(r) : "v"(a), "v"(b));
  return r;
}

union FragU { unsigned u[4]; bhalf8 v; };

__device__ __forceinline__ void gload_lds16(const void* g, void* l) {
#if __has_builtin(__builtin_amdgcn_global_load_lds)
  __builtin_amdgcn_global_load_lds(
      (const __attribute__((address_space(1))) unsigned*)g,
      (__attribute__((address_space(3))) unsigned*)l, 16, 0, 0);
#else
  *(uint4*)l = *(const uint4*)g;
#endif
}

// ---------------- prep: fp32 K/V -> bf16 swizzled tiles in ws ----------------
__global__ __launch_bounds__(256, 2) void fa_prep(
    const float* __restrict__ K, const float* __restrict__ V,
    unsigned short* __restrict__ Kb, unsigned short* __restrict__ Vb) {
  const int tid = threadIdx.x;
  const int bid = blockIdx.x;
  const int bh = bid >> 5, kt = bid & 31;
  __shared__ __align__(16) unsigned short SS[16384];  // Kl[0..8191], Vt[8192..16383]
  __shared__ __align__(16) float VS[128 * 68];        // fp32 V tile, padded stride 68
  unsigned short* Kl = SS;
  unsigned short* Vt = SS + 8192;
  const int base = bh * (T_SEQ * DIM) + kt * (KTILE * DIM);

  // K tile: row kv, 8 chunks of 8 bf16, chunk swizzle c' = c ^ (kv&7)
  {
    const float4* kp4 = reinterpret_cast<const float4*>(K + base);
    float4 kx[8];
#pragma unroll
    for (int c = 0; c < 8; ++c) kx[c] = kp4[tid + 256 * c];
#pragma unroll
    for (int c = 0; c < 8; ++c) {
      int f4 = tid + 256 * c;
      int kv = f4 >> 4;
      int d0 = (f4 & 15) << 2;
      unsigned lo = pk2bf(kx[c].x, kx[c].y);
      unsigned hi = pk2bf(kx[c].z, kx[c].w);
      unsigned long long u64 = (unsigned long long)lo | ((unsigned long long)hi << 32);
      int idx = (kv << 6) | ((((d0 >> 3) ^ (kv & 7)) << 3) | (d0 & 7));
      *reinterpret_cast<unsigned long long*>(&Kl[idx]) = u64;
    }
  }
  // V tile: coalesced load, fp32 transpose staging in LDS
  {
    const float4* vp4 = reinterpret_cast<const float4*>(V + base);
#pragma unroll
    for (int c = 0; c < 8; ++c) {
      float4 x = vp4[tid + 256 * c];
      int f4 = tid + 256 * c;
      int kv = f4 >> 4;
      int d0 = (f4 & 15) << 2;
      *reinterpret_cast<float4*>(&VS[kv * 68 + d0]) = x;
    }
  }
  __syncthreads();
  // read columns from VS (sigma-permuted kv), pack into swizzled Vt slots
  {
    const int s0 = (tid & 63) << 1;        // slot pair (even)
    const int db = (tid >> 6) << 4;        // d base (16 per group)
    const int kva = sig23(s0);             // sigma on even slot (bit0 unaffected)
    const int kvb = kva + 1;
    float4 va[4], vb[4];
#pragma unroll
    for (int sg = 0; sg < 4; ++sg) {
      va[sg] = *reinterpret_cast<const float4*>(&VS[kva * 68 + db + 4 * sg]);
      vb[sg] = *reinterpret_cast<const float4*>(&VS[kvb * 68 + db + 4 * sg]);
    }
    const float* vaf = reinterpret_cast<const float*>(va);
    const float* vbf = reinterpret_cast<const float*>(vb);
#pragma unroll
    for (int j = 0; j < 16; ++j) {
      int d = db + j;
      unsigned u = pk2bf(vaf[j], vbf[j]);  // low = slot s0, high = s0+1
      int idx = (d << 7) | ((((s0 >> 3) ^ (d & 15)) << 3) | (s0 & 7));
      *reinterpret_cast<unsigned*>(&Vt[idx]) = u;
    }
  }
  __syncthreads();
  // linear dump to global (coalesced uint4)
  const uint4* S4 = reinterpret_cast<const uint4*>(SS);
  uint4* KbT = reinterpret_cast<uint4*>(Kb + (size_t)(bh * 32 + kt) * 8192);
  uint4* VbT = reinterpret_cast<uint4*>(Vb + (size_t)(bh * 32 + kt) * 8192);
#pragma unroll
  for (int i = 0; i < 4; ++i) KbT[tid + 256 * i] = S4[tid + 256 * i];
#pragma unroll
  for (int i = 0; i < 4; ++i) VbT[tid + 256 * i] = S4[1024 + tid + 256 * i];
}

// ---------------- main: ONE block per (bh, pair) — diagonal-paired rows ------
// v9: v8b per-iteration body UNCHANGED (ds_write staging — v8's gload_lds@512
// killed containers twice; ds_write version verified). DECOMPOSITION FIX:
// v8b's counters showed busy-CU throughput ~1.7x better than v7 but
// occupancy 20.6% from static imbalance (grid == residency, block work
// 2..32 iters). Diagonal pairing: block handles qt=15-pr THEN qt=pr, so
// every block does exactly (2(15-pr)+2)+(2pr+2) = 34 kv-iters. Grid 256
// (1 block/CU, 8 waves), zero tail. Same total work (8704 iters).
__global__ __launch_bounds__(512, 2) void fa_main2(
    const float* __restrict__ Q, const unsigned short* __restrict__ Kb,
    const unsigned short* __restrict__ Vb, float* __restrict__ O) {
  const int tid  = threadIdx.x;
  const int w    = tid >> 6;               // 0..7
  const int lane = tid & 63;
  const int n    = lane & 31;
  const int h    = lane >> 5;
  const int bid  = blockIdx.x;
  const int bh   = bid & (NBH - 1);
  const int pr   = bid >> 5;               // 0..7

  const int base = bh * (T_SEQ * DIM);

  __shared__ __align__(16) unsigned short Kl[KTILE * DIM];
  __shared__ __align__(16) unsigned short Vt[DIM * KTILE];

  const int qloc = w * 32 + n;             // 0..255
  const float cs = 0.125f * 1.44269504088896340736f;
  const int sw = n & 15;
  uint4* const kl4 = reinterpret_cast<uint4*>(Kl);
  uint4* const vl4 = reinterpret_cast<uint4*>(Vt);

  floatx16 zf;
#pragma unroll
  for (int i = 0; i < 16; ++i) zf[i] = 0.f;

#pragma unroll 1
  for (int p = 0; p < 2; ++p) {
    const int qt   = p ? pr : (NQT2 - 1 - pr);   // heavy half first
    const int kend = 2 * qt + 2;                 // kv tiles 0..2qt+1
    const int qrow = qt * QTILE + qloc;

    FragU qf[4];
    {
      const float* qp = Q + base + qrow * DIM + h * 8;
#pragma unroll
      for (int ks = 0; ks < 4; ++ks) {
        float4 a = *reinterpret_cast<const float4*>(qp + 16 * ks);
        float4 b = *reinterpret_cast<const float4*>(qp + 16 * ks + 4);
        qf[ks].u[0] = cvtpk(a.x * cs, a.y * cs);
        qf[ks].u[1] = cvtpk(a.z * cs, a.w * cs);
        qf[ks].u[2] = cvtpk(b.x * cs, b.y * cs);
        qf[ks].u[3] = cvtpk(b.z * cs, b.w * cs);
      }
    }

    floatx16 o0, o1;
#pragma unroll
    for (int i = 0; i < 16; ++i) { o0[i] = 0.f; o1[i] = 0.f; }
    float s_run = 0.f;

    for (int kt = 0; kt < kend; ++kt) {
      __syncthreads();   // all waves done reading previous tile (or phase)
      {
        // tile = 8192 shorts = 1024 uint4; 512 threads x 2 each; coalesced
        const uint4* kb4 = reinterpret_cast<const uint4*>(Kb + (size_t)((bh << 5) + kt) * 8192);
        const uint4* vb4 = reinterpret_cast<const uint4*>(Vb + (size_t)((bh << 5) + kt) * 8192);
        uint4 ka = kb4[tid], kbx = kb4[tid + 512];
        uint4 va = vb4[tid], vbx = vb4[tid + 512];
        kl4[tid] = ka;  kl4[tid + 512] = kbx;
        vl4[tid] = va;  vl4[tid + 512] = vbx;
      }
      __syncthreads();

      // S^T = K * Q^T (zero-C init via loop-invariant zf)
      floatx16 st[4];
#pragma unroll
      for (int tt = 0; tt < 4; ++tt) {
        const bhalf8 kf0 = *reinterpret_cast<const bhalf8*>(
            &Kl[((32 * tt + n) << 6) | (((0 + h) ^ (n & 7)) << 3)]);
        const bhalf8 kf1 = *reinterpret_cast<const bhalf8*>(
            &Kl[((32 * tt + n) << 6) | (((2 + h) ^ (n & 7)) << 3)]);
        const bhalf8 kf2 = *reinterpret_cast<const bhalf8*>(
            &Kl[((32 * tt + n) << 6) | (((4 + h) ^ (n & 7)) << 3)]);
        const bhalf8 kf3 = *reinterpret_cast<const bhalf8*>(
            &Kl[((32 * tt + n) << 6) | (((6 + h) ^ (n & 7)) << 3)]);
        __builtin_amdgcn_s_setprio(1);
        floatx16 acc = __builtin_amdgcn_mfma_f32_32x32x16_bf16(kf0, qf[0].v, zf, 0, 0, 0);
        acc = __builtin_amdgcn_mfma_f32_32x32x16_bf16(kf1, qf[1].v, acc, 0, 0, 0);
        acc = __builtin_amdgcn_mfma_f32_32x32x16_bf16(kf2, qf[2].v, acc, 0, 0, 0);
        acc = __builtin_amdgcn_mfma_f32_32x32x16_bf16(kf3, qf[3].v, acc, 0, 0, 0);
        __builtin_amdgcn_s_setprio(0);
        st[tt] = acc;
      }

      if (kt >= kend - 2) {  // causal mask: only last two kv tiles cross diag
        const int thr = qrow - (kt << 7);  // mask kvloc > thr
#pragma unroll
        for (int tt = 0; tt < 4; ++tt)
#pragma unroll
          for (int r = 0; r < 16; ++r) {
            int kvloc = 32 * tt + (r & 3) + 8 * (r >> 2) + 4 * h;
            st[tt][r] = (kvloc > thr) ? -__builtin_inff() : st[tt][r];
          }
      }

      // softmax numerator (no max shift): p = exp2(score)
      float psum = 0.f;
#pragma unroll
      for (int tt = 0; tt < 4; ++tt)
#pragma unroll
        for (int r = 0; r < 16; ++r) {
          float pv = EXP2F(st[tt][r]);
          st[tt][r] = pv;
          psum += pv;
        }
      psum += __shfl_xor(psum, 32, 64);
      s_run += psum;

      // P -> bf16 B-fragments (cvtpk: 1 instr/pair) + PV
#pragma unroll
      for (int tt = 0; tt < 4; ++tt) {
        FragU b0, b1;
        b0.u[0] = cvtpk(st[tt][0],  st[tt][1]);
        b0.u[1] = cvtpk(st[tt][2],  st[tt][3]);
        b0.u[2] = cvtpk(st[tt][4],  st[tt][5]);
        b0.u[3] = cvtpk(st[tt][6],  st[tt][7]);
        b1.u[0] = cvtpk(st[tt][8],  st[tt][9]);
        b1.u[1] = cvtpk(st[tt][10], st[tt][11]);
        b1.u[2] = cvtpk(st[tt][12], st[tt][13]);
        b1.u[3] = cvtpk(st[tt][14], st[tt][15]);

        const bhalf8 v00 = *reinterpret_cast<const bhalf8*>(
            &Vt[(n << 7) | (((4 * tt + 0 + h) ^ sw) << 3)]);
        const bhalf8 v01 = *reinterpret_cast<const bhalf8*>(
            &Vt[(n << 7) | (((4 * tt + 2 + h) ^ sw) << 3)]);
        const bhalf8 v10 = *reinterpret_cast<const bhalf8*>(
            &Vt[((32 + n) << 7) | (((4 * tt + 0 + h) ^ sw) << 3)]);
        const bhalf8 v11 = *reinterpret_cast<const bhalf8*>(
            &Vt[((32 + n) << 7) | (((4 * tt + 2 + h) ^ sw) << 3)]);

        __builtin_amdgcn_s_setprio(1);
        o0 = __builtin_amdgcn_mfma_f32_32x32x16_bf16(v00, b0.v, o0, 0, 0, 0);
        o0 = __builtin_amdgcn_mfma_f32_32x32x16_bf16(v01, b1.v, o0, 0, 0, 0);
        o1 = __builtin_amdgcn_mfma_f32_32x32x16_bf16(v10, b0.v, o1, 0, 0, 0);
        o1 = __builtin_amdgcn_mfma_f32_32x32x16_bf16(v11, b1.v, o1, 0, 0, 0);
        __builtin_amdgcn_s_setprio(0);
      }
    }

    // epilogue: normalized fp32 O, written directly
    const float inv = 1.0f / s_run;
    float* op = O + base + qrow * DIM;
#pragma unroll
    for (int g = 0; g < 4; ++g) {
      float4 x, y;
      x.x = o0[4 * g] * inv;  x.y = o0[4 * g + 1] * inv;
      x.z = o0[4 * g + 2] * inv;  x.w = o0[4 * g + 3] * inv;
      y.x = o1[4 * g] * inv;  y.y = o1[4 * g + 1] * inv;
      y.z = o1[4 * g + 2] * inv;  y.w = o1[4 * g + 3] * inv;
      *reinterpret_cast<float4*>(op + 8 * g + 4 * h)      = x;
      *reinterpret_cast<float4*>(op + 32 + 8 * g + 4 * h) = y;
    }
  }
}

// ---------------- fallback (monolithic, sigma-permuted V) --------------------
__global__ __launch_bounds__(256, 2) void fa_mono(
    const float* __restrict__ Q, const float* __restrict__ K,
    const float* __restrict__ V, float* __restrict__ O) {
  const int tid  = threadIdx.x;
  const int w    = tid >> 6;
  const int lane = tid & 63;
  const int n    = lane & 31;
  const int h    = lane >> 5;
  const int bid  = blockIdx.x;
  const int bh   = bid & (NBH - 1);
  const int qt   = (NQT - 1) - (bid >> 5);

  const int base = bh * (T_SEQ * DIM);
  __shared__ __align__(16) unsigned short Kl[KTILE * DIM];
  __shared__ __align__(16) unsigned short Vt[DIM * KTILE];

  const int qrow = qt * 128 + w * 32 + n;
  const float cs = 0.125f * 1.44269504088896340736f;
  FragU qf[4];
  {
    const float* qp = Q + base + qrow * DIM + h * 8;
#pragma unroll
    for (int ks = 0; ks < 4; ++ks) {
      float4 a = *reinterpret_cast<const float4*>(qp + 16 * ks);
      float4 b = *reinterpret_cast<const float4*>(qp + 16 * ks + 4);
      qf[ks].u[0] = pk2bf(a.x * cs, a.y * cs);
      qf[ks].u[1] = pk2bf(a.z * cs, a.w * cs);
      qf[ks].u[2] = pk2bf(b.x * cs, b.y * cs);
      qf[ks].u[3] = pk2bf(b.z * cs, b.w * cs);
    }
  }

  floatx16 o0, o1;
#pragma unroll
  for (int i = 0; i < 16; ++i) { o0[i] = 0.f; o1[i] = 0.f; }
  float s_run = 0.f;

  for (int kt = 0; kt <= qt; ++kt) {
    __syncthreads();
    {
      const float4* kp4 = reinterpret_cast<const float4*>(K + base + kt * (KTILE * DIM));
      float4 kx[8];
#pragma unroll
      for (int c = 0; c < 8; ++c) kx[c] = kp4[tid + 256 * c];
#pragma unroll
      for (int c = 0; c < 8; ++c) {
        int f4 = tid + 256 * c;
        int kv = f4 >> 4;
        int d0 = (f4 & 15) << 2;
        unsigned lo = pk2bf(kx[c].x, kx[c].y);
        unsigned hi = pk2bf(kx[c].z, kx[c].w);
        unsigned long long u64 = (unsigned long long)lo | ((unsigned long long)hi << 32);
        int idx = (kv << 6) | ((((d0 >> 3) ^ (kv & 7)) << 3) | (d0 & 7));
        *reinterpret_cast<unsigned long long*>(&Kl[idx]) = u64;
      }
      const int s0 = (tid & 63) << 1;
      const int db = (tid >> 6) << 4;
      const int kva = sig23(s0);
      const float* vr0 = V + base + kt * (KTILE * DIM) + kva * DIM + db;
      const float* vr1 = vr0 + DIM;
      float4 va[4], vb[4];
#pragma unroll
      for (int sg = 0; sg < 4; ++sg) {
        va[sg] = *reinterpret_cast<const float4*>(vr0 + 4 * sg);
        vb[sg] = *reinterpret_cast<const float4*>(vr1 + 4 * sg);
      }
      const float* vaf = reinterpret_cast<const float*>(va);
      const float* vbf = reinterpret_cast<const float*>(vb);
#pragma unroll
      for (int j = 0; j < 16; ++j) {
        int d = db + j;
        unsigned u = pk2bf(vaf[j], vbf[j]);
        int idx = (d << 7) | ((((s0 >> 3) ^ (d & 15)) << 3) | (s0 & 7));
        *reinterpret_cast<unsigned*>(&Vt[idx]) = u;
      }
    }
    __syncthreads();

    floatx16 st[4];
#pragma unroll
    for (int tt = 0; tt < 4; ++tt) {
      floatx16 acc;
#pragma unroll
      for (int i = 0; i < 16; ++i) acc[i] = 0.f;
#pragma unroll
      for (int ks = 0; ks < 4; ++ks) {
        const bhalf8 kfrag = *reinterpret_cast<const bhalf8*>(
            &Kl[((32 * tt + n) << 6) | (((2 * ks + h) ^ (n & 7)) << 3)]);
        acc = __builtin_amdgcn_mfma_f32_32x32x16_bf16(kfrag, qf[ks].v, acc, 0, 0, 0);
      }
      st[tt] = acc;
    }

    if (kt == qt) {
#pragma unroll
      for (int tt = 0; tt < 4; ++tt)
#pragma unroll
        for (int r = 0; r < 16; ++r) {
          int kvloc = 32 * tt + (r & 3) + 8 * (r >> 2) + 4 * h;
          st[tt][r] = (kvloc > 32 * w + n) ? -__builtin_inff() : st[tt][r];
        }
    }

    float psum = 0.f;
#pragma unroll
    for (int tt = 0; tt < 4; ++tt)
#pragma unroll
      for (int r = 0; r < 16; ++r) {
        float p = EXP2F(st[tt][r]);
        st[tt][r] = p;
        psum += p;
      }
    psum += __shfl_xor(psum, 32, 64);
    s_run += psum;

#pragma unroll
    for (int tt = 0; tt < 4; ++tt) {
      FragU b0, b1;
      b0.u[0] = pk2bf(st[tt][0],  st[tt][1]);
      b0.u[1] = pk2bf(st[tt][2],  st[tt][3]);
      b0.u[2] = pk2bf(st[tt][4],  st[tt][5]);
      b0.u[3] = pk2bf(st[tt][6],  st[tt][7]);
      b1.u[0] = pk2bf(st[tt][8],  st[tt][9]);
      b1.u[1] = pk2bf(st[tt][10], st[tt][11]);
      b1.u[2] = pk2bf(st[tt][12], st[tt][13]);
      b1.u[3] = pk2bf(st[tt][14], st[tt][15]);

      const int sw = n & 15;
      const bhalf8 v00 = *reinterpret_cast<const bhalf8*>(
          &Vt[(n << 7) | (((4 * tt + 0 + h) ^ sw) << 3)]);
      const bhalf8 v01 = *reinterpret_cast<const bhalf8*>(
          &Vt[(n << 7) | (((4 * tt + 2 + h) ^ sw) << 3)]);
      const bhalf8 v10 = *reinterpret_cast<const bhalf8*>(
          &Vt[((32 + n) << 7) | (((4 * tt + 0 + h) ^ sw) << 3)]);
      const bhalf8 v11 = *reinterpret_cast<const bhalf8*>(
          &Vt[((32 + n) << 7) | (((4 * tt + 2 + h) ^ sw) << 3)]);
      o0 = __builtin_amdgcn_mfma_f32_32x32x16_bf16(v00, b0.v, o0, 0, 0, 0);
      o0 = __builtin_amdgcn_mfma_f32_32x32x16_bf16(v01, b1.v, o0, 0, 0, 0);
      o1 = __builtin_amdgcn_mfma_f32_32x32x16_bf16(v10, b0.v, o1, 0, 0, 0);
      o1 = __builtin_amdgcn_mfma_f32_32x32x16_bf16(v11, b1.v, o1, 0, 0, 0);
    }
  }

  const float inv = 1.0f / s_run;
  float* op = O + base + qrow * DIM;
#pragma unroll
  for (int g = 0; g < 4; ++g) {
    float4 x, y;
    x.x = o0[4 * g] * inv;  x.y = o0[4 * g + 1] * inv;
    x.z = o0[4 * g + 2] * inv;  x.w = o0[4 * g + 3] * inv;
    y.x = o1[4 * g] * inv;  y.y = o1[4 * g + 1] * inv;
    y.z = o1[4 * g + 2] * inv;  y.w = o1[4 * g + 3] * inv;
    *reinterpret_cast<float4*>(op + 8 * g + 4 * h)      = x;
    *reinterpret_cast<float4*>(op + 32 + 8 * g + 4 * h) = y;
  }
}

extern "C" void kernel_launch(void* const* d_in, const int* in_sizes, int n_in,
                              void* d_out, int out_size, void* d_ws, size_t ws_size,
                              hipStream_t stream) {
  (void)in_sizes; (void)n_in; (void)out_size;
  const float* Q = (const float*)d_in[0];
  const float* K = (const float*)d_in[1];
  const float* V = (const float*)d_in[2];
  float* O = (float*)d_out;

  // ws layout (bytes): Kb[16MB] | Vb[16MB]
  const size_t OFF_KB = 0;
  const size_t OFF_VB = 16777216;
  const size_t NEED   = 33554432;

  if (ws_size >= NEED) {
    unsigned short* Kb = (unsigned short*)((char*)d_ws + OFF_KB);
    unsigned short* Vb = (unsigned short*)((char*)d_ws + OFF_VB);
    fa_prep<<<dim3(NBH * NQT), dim3(256), 0, stream>>>(K, V, Kb, Vb);
    fa_main2<<<dim3(NBH * NPAIR), dim3(512), 0, stream>>>(Q, Kb, Vb, O);
  } else {
    fa_mono<<<dim3(NQT * NBH), dim3(256), 0, stream>>>(Q, K, V, O);
  }
}

// Round 11
// 208.947 us; speedup vs baseline: 1.0055x; 1.0038x over previous
//
#include <hip/hip_runtime.h>

#define T_SEQ 4096
#define DIM   64
#define NQT   32     // T / 128
#define QTILE 256    // 256 q-rows per block (8 waves)
#define KTILE 128    // base kv tile in ws layout (prep unchanged)
#define NBH   32     // B*H
#define NQT2  16     // T / 256
#define NPAIR 8      // diagonal pairs (qt, 15-qt)

typedef __attribute__((ext_vector_type(8)))  short bhalf8;
typedef __attribute__((ext_vector_type(16))) float floatx16;

#if __has_builtin(__builtin_amdgcn_exp2f)
#define EXP2F(x) __builtin_amdgcn_exp2f(x)
#else
#define EXP2F(x) exp2f(x)
#endif

// sigma: swap bits 2<->3 (kv permutation matching MFMA C->B register order)
__device__ __forceinline__ int sig23(int s) {
  return (s & ~12) | ((s & 4) << 1) | ((s & 8) >> 1);
}

// pack two fp32 -> two bf16 (round-half-up) in one v_perm_b32
__device__ __forceinline__ unsigned pk2bf(float a, float b) {
  unsigned ua = __builtin_bit_cast(unsigned, a) + 0x8000u;
  unsigned ub = __builtin_bit_cast(unsigned, b) + 0x8000u;
  return __builtin_amdgcn_perm(ub, ua, 0x07060302u);
}

// pack two fp32 -> two bf16 (RNE) in ONE instruction (no builtin on gfx950)
__device__ __forceinline__ unsigned cvtpk(float a, float b) {
  unsigned r;
  asm("v_cvt_pk_bf16_f32 %0, %1, %2" : "=v"(r) : "v"(a), "v"(b));
  return r;
}

union FragU { unsigned u[4]; bhalf8 v; };

__device__ __forceinline__ void gload_lds16(const void* g, void* l) {
#if __has_builtin(__builtin_amdgcn_global_load_lds)
  __builtin_amdgcn_global_load_lds(
      (const __attribute__((address_space(1))) unsigned*)g,
      (__attribute__((address_space(3))) unsigned*)l, 16, 0, 0);
#else
  *(uint4*)l = *(const uint4*)g;
#endif
}

// ---------------- prep: fp32 K/V -> bf16 swizzled tiles in ws ----------------
__global__ __launch_bounds__(256, 2) void fa_prep(
    const float* __restrict__ K, const float* __restrict__ V,
    unsigned short* __restrict__ Kb, unsigned short* __restrict__ Vb) {
  const int tid = threadIdx.x;
  const int bid = blockIdx.x;
  const int bh = bid >> 5, kt = bid & 31;
  __shared__ __align__(16) unsigned short SS[16384];  // Kl[0..8191], Vt[8192..16383]
  __shared__ __align__(16) float VS[128 * 68];        // fp32 V tile, padded stride 68
  unsigned short* Kl = SS;
  unsigned short* Vt = SS + 8192;
  const int base = bh * (T_SEQ * DIM) + kt * (KTILE * DIM);

  // K tile: row kv, 8 chunks of 8 bf16, chunk swizzle c' = c ^ (kv&7)
  {
    const float4* kp4 = reinterpret_cast<const float4*>(K + base);
    float4 kx[8];
#pragma unroll
    for (int c = 0; c < 8; ++c) kx[c] = kp4[tid + 256 * c];
#pragma unroll
    for (int c = 0; c < 8; ++c) {
      int f4 = tid + 256 * c;
      int kv = f4 >> 4;
      int d0 = (f4 & 15) << 2;
      unsigned lo = pk2bf(kx[c].x, kx[c].y);
      unsigned hi = pk2bf(kx[c].z, kx[c].w);
      unsigned long long u64 = (unsigned long long)lo | ((unsigned long long)hi << 32);
      int idx = (kv << 6) | ((((d0 >> 3) ^ (kv & 7)) << 3) | (d0 & 7));
      *reinterpret_cast<unsigned long long*>(&Kl[idx]) = u64;
    }
  }
  // V tile: coalesced load, fp32 transpose staging in LDS
  {
    const float4* vp4 = reinterpret_cast<const float4*>(V + base);
#pragma unroll
    for (int c = 0; c < 8; ++c) {
      float4 x = vp4[tid + 256 * c];
      int f4 = tid + 256 * c;
      int kv = f4 >> 4;
      int d0 = (f4 & 15) << 2;
      *reinterpret_cast<float4*>(&VS[kv * 68 + d0]) = x;
    }
  }
  __syncthreads();
  // read columns from VS (sigma-permuted kv), pack into swizzled Vt slots
  {
    const int s0 = (tid & 63) << 1;        // slot pair (even)
    const int db = (tid >> 6) << 4;        // d base (16 per group)
    const int kva = sig23(s0);             // sigma on even slot (bit0 unaffected)
    const int kvb = kva + 1;
    float4 va[4], vb[4];
#pragma unroll
    for (int sg = 0; sg < 4; ++sg) {
      va[sg] = *reinterpret_cast<const float4*>(&VS[kva * 68 + db + 4 * sg]);
      vb[sg] = *reinterpret_cast<const float4*>(&VS[kvb * 68 + db + 4 * sg]);
    }
    const float* vaf = reinterpret_cast<const float*>(va);
    const float* vbf = reinterpret_cast<const float*>(vb);
#pragma unroll
    for (int j = 0; j < 16; ++j) {
      int d = db + j;
      unsigned u = pk2bf(vaf[j], vbf[j]);  // low = slot s0, high = s0+1
      int idx = (d << 7) | ((((s0 >> 3) ^ (d & 15)) << 3) | (s0 & 7));
      *reinterpret_cast<unsigned*>(&Vt[idx]) = u;
    }
  }
  __syncthreads();
  // linear dump to global (coalesced uint4)
  const uint4* S4 = reinterpret_cast<const uint4*>(SS);
  uint4* KbT = reinterpret_cast<uint4*>(Kb + (size_t)(bh * 32 + kt) * 8192);
  uint4* VbT = reinterpret_cast<uint4*>(Vb + (size_t)(bh * 32 + kt) * 8192);
#pragma unroll
  for (int i = 0; i < 4; ++i) KbT[tid + 256 * i] = S4[tid + 256 * i];
#pragma unroll
  for (int i = 0; i < 4; ++i) VbT[tid + 256 * i] = S4[1024 + tid + 256 * i];
}

// ---------------- main: ONE block per (bh, pair) — paired rows, KTILE 256 ----
// v11: v9's balance (diagonal pairing: every block exactly 17 staging events)
// + halved event count via 256-kv double-tile staging (64KB LDS: two 128-kv
// segments per K and V, prep layout unchanged). v9's counters quantified the
// exposed per-event stall at ~1.4us (1 block/CU: 3.09 us/iter vs v8b's 1.72
// with 2-block overlap); doubling compute per event halves that tax. Compute
// body = v9's verified body run per half-segment. Staging stays ds_write
// (v8's gload_lds@512 killed containers twice — quarantined).
__global__ __launch_bounds__(512, 2) void fa_main2(
    const float* __restrict__ Q, const unsigned short* __restrict__ Kb,
    const unsigned short* __restrict__ Vb, float* __restrict__ O) {
  const int tid  = threadIdx.x;
  const int w    = tid >> 6;               // 0..7
  const int lane = tid & 63;
  const int n    = lane & 31;
  const int h    = lane >> 5;
  const int bid  = blockIdx.x;
  const int bh   = bid & (NBH - 1);
  const int pr   = bid >> 5;               // 0..7

  const int base = bh * (T_SEQ * DIM);

  __shared__ __align__(16) unsigned short Kl[2 * KTILE * DIM];  // 32KB, 2 segments
  __shared__ __align__(16) unsigned short Vt[2 * DIM * KTILE];  // 32KB, 2 segments

  const int qloc = w * 32 + n;             // 0..255
  const float cs = 0.125f * 1.44269504088896340736f;
  const int sw = n & 15;
  uint4* const kl4 = reinterpret_cast<uint4*>(Kl);
  uint4* const vl4 = reinterpret_cast<uint4*>(Vt);

  floatx16 zf;
#pragma unroll
  for (int i = 0; i < 16; ++i) zf[i] = 0.f;

#pragma unroll 1
  for (int p = 0; p < 2; ++p) {
    const int qt    = p ? pr : (NQT2 - 1 - pr);   // heavy half first
    const int kend2 = qt + 1;                     // 256-kv double-tiles
    const int qrow  = qt * QTILE + qloc;

    FragU qf[4];
    {
      const float* qp = Q + base + qrow * DIM + h * 8;
#pragma unroll
      for (int ks = 0; ks < 4; ++ks) {
        float4 a = *reinterpret_cast<const float4*>(qp + 16 * ks);
        float4 b = *reinterpret_cast<const float4*>(qp + 16 * ks + 4);
        qf[ks].u[0] = cvtpk(a.x * cs, a.y * cs);
        qf[ks].u[1] = cvtpk(a.z * cs, a.w * cs);
        qf[ks].u[2] = cvtpk(b.x * cs, b.y * cs);
        qf[ks].u[3] = cvtpk(b.z * cs, b.w * cs);
      }
    }

    floatx16 o0, o1;
#pragma unroll
    for (int i = 0; i < 16; ++i) { o0[i] = 0.f; o1[i] = 0.f; }
    float s_run = 0.f;

#pragma unroll 1
    for (int kt2 = 0; kt2 < kend2; ++kt2) {
      __syncthreads();   // all waves done reading previous double-tile
      {
        // two consecutive 16KB tiles = 32KB contiguous per operand;
        // 2048 uint4 each; 512 threads x 4; coalesced loads + linear ds_write
        const uint4* kb4 = reinterpret_cast<const uint4*>(Kb + (size_t)((bh << 5) + 2 * kt2) * 8192);
        const uint4* vb4 = reinterpret_cast<const uint4*>(Vb + (size_t)((bh << 5) + 2 * kt2) * 8192);
        uint4 k0 = kb4[tid], k1 = kb4[tid + 512], k2 = kb4[tid + 1024], k3 = kb4[tid + 1536];
        uint4 v0 = vb4[tid], v1 = vb4[tid + 512], v2 = vb4[tid + 1024], v3 = vb4[tid + 1536];
        kl4[tid] = k0;  kl4[tid + 512] = k1;  kl4[tid + 1024] = k2;  kl4[tid + 1536] = k3;
        vl4[tid] = v0;  vl4[tid + 512] = v1;  vl4[tid + 1024] = v2;  vl4[tid + 1536] = v3;
      }
      __syncthreads();

      const bool diag = (kt2 == kend2 - 1);   // only last double-tile crosses
      float psum = 0.f;

#pragma unroll
      for (int half = 0; half < 2; ++half) {
        const unsigned short* Ks = Kl + half * 8192;
        const unsigned short* Vs = Vt + half * 8192;

        // S^T = K * Q^T (zero-C init via loop-invariant zf)
        floatx16 st[4];
#pragma unroll
        for (int tt = 0; tt < 4; ++tt) {
          const bhalf8 kf0 = *reinterpret_cast<const bhalf8*>(
              &Ks[((32 * tt + n) << 6) | (((0 + h) ^ (n & 7)) << 3)]);
          const bhalf8 kf1 = *reinterpret_cast<const bhalf8*>(
              &Ks[((32 * tt + n) << 6) | (((2 + h) ^ (n & 7)) << 3)]);
          const bhalf8 kf2 = *reinterpret_cast<const bhalf8*>(
              &Ks[((32 * tt + n) << 6) | (((4 + h) ^ (n & 7)) << 3)]);
          const bhalf8 kf3 = *reinterpret_cast<const bhalf8*>(
              &Ks[((32 * tt + n) << 6) | (((6 + h) ^ (n & 7)) << 3)]);
          __builtin_amdgcn_s_setprio(1);
          floatx16 acc = __builtin_amdgcn_mfma_f32_32x32x16_bf16(kf0, qf[0].v, zf, 0, 0, 0);
          acc = __builtin_amdgcn_mfma_f32_32x32x16_bf16(kf1, qf[1].v, acc, 0, 0, 0);
          acc = __builtin_amdgcn_mfma_f32_32x32x16_bf16(kf2, qf[2].v, acc, 0, 0, 0);
          acc = __builtin_amdgcn_mfma_f32_32x32x16_bf16(kf3, qf[3].v, acc, 0, 0, 0);
          __builtin_amdgcn_s_setprio(0);
          st[tt] = acc;
        }

        if (diag) {  // causal mask within the diagonal double-tile
          const int thr = qloc - (half << 7);   // may be negative: fully masked
#pragma unroll
          for (int tt = 0; tt < 4; ++tt)
#pragma unroll
            for (int r = 0; r < 16; ++r) {
              int kvloc = 32 * tt + (r & 3) + 8 * (r >> 2) + 4 * h;
              st[tt][r] = (kvloc > thr) ? -__builtin_inff() : st[tt][r];
            }
        }

        // softmax numerator (no max shift): p = exp2(score)
#pragma unroll
        for (int tt = 0; tt < 4; ++tt)
#pragma unroll
          for (int r = 0; r < 16; ++r) {
            float pv = EXP2F(st[tt][r]);
            st[tt][r] = pv;
            psum += pv;
          }

        // P -> bf16 B-fragments (cvtpk: 1 instr/pair) + PV
#pragma unroll
        for (int tt = 0; tt < 4; ++tt) {
          FragU b0, b1;
          b0.u[0] = cvtpk(st[tt][0],  st[tt][1]);
          b0.u[1] = cvtpk(st[tt][2],  st[tt][3]);
          b0.u[2] = cvtpk(st[tt][4],  st[tt][5]);
          b0.u[3] = cvtpk(st[tt][6],  st[tt][7]);
          b1.u[0] = cvtpk(st[tt][8],  st[tt][9]);
          b1.u[1] = cvtpk(st[tt][10], st[tt][11]);
          b1.u[2] = cvtpk(st[tt][12], st[tt][13]);
          b1.u[3] = cvtpk(st[tt][14], st[tt][15]);

          const bhalf8 v00 = *reinterpret_cast<const bhalf8*>(
              &Vs[(n << 7) | (((4 * tt + 0 + h) ^ sw) << 3)]);
          const bhalf8 v01 = *reinterpret_cast<const bhalf8*>(
              &Vs[(n << 7) | (((4 * tt + 2 + h) ^ sw) << 3)]);
          const bhalf8 v10 = *reinterpret_cast<const bhalf8*>(
              &Vs[((32 + n) << 7) | (((4 * tt + 0 + h) ^ sw) << 3)]);
          const bhalf8 v11 = *reinterpret_cast<const bhalf8*>(
              &Vs[((32 + n) << 7) | (((4 * tt + 2 + h) ^ sw) << 3)]);

          __builtin_amdgcn_s_setprio(1);
          o0 = __builtin_amdgcn_mfma_f32_32x32x16_bf16(v00, b0.v, o0, 0, 0, 0);
          o0 = __builtin_amdgcn_mfma_f32_32x32x16_bf16(v01, b1.v, o0, 0, 0, 0);
          o1 = __builtin_amdgcn_mfma_f32_32x32x16_bf16(v10, b0.v, o1, 0, 0, 0);
          o1 = __builtin_amdgcn_mfma_f32_32x32x16_bf16(v11, b1.v, o1, 0, 0, 0);
          __builtin_amdgcn_s_setprio(0);
        }
      }

      psum += __shfl_xor(psum, 32, 64);
      s_run += psum;
    }

    // epilogue: normalized fp32 O, written directly
    const float inv = 1.0f / s_run;
    float* op = O + base + qrow * DIM;
#pragma unroll
    for (int g = 0; g < 4; ++g) {
      float4 x, y;
      x.x = o0[4 * g] * inv;  x.y = o0[4 * g + 1] * inv;
      x.z = o0[4 * g + 2] * inv;  x.w = o0[4 * g + 3] * inv;
      y.x = o1[4 * g] * inv;  y.y = o1[4 * g + 1] * inv;
      y.z = o1[4 * g + 2] * inv;  y.w = o1[4 * g + 3] * inv;
      *reinterpret_cast<float4*>(op + 8 * g + 4 * h)      = x;
      *reinterpret_cast<float4*>(op + 32 + 8 * g + 4 * h) = y;
    }
  }
}

// ---------------- fallback (monolithic, sigma-permuted V) --------------------
__global__ __launch_bounds__(256, 2) void fa_mono(
    const float* __restrict__ Q, const float* __restrict__ K,
    const float* __restrict__ V, float* __restrict__ O) {
  const int tid  = threadIdx.x;
  const int w    = tid >> 6;
  const int lane = tid & 63;
  const int n    = lane & 31;
  const int h    = lane >> 5;
  const int bid  = blockIdx.x;
  const int bh   = bid & (NBH - 1);
  const int qt   = (NQT - 1) - (bid >> 5);

  const int base = bh * (T_SEQ * DIM);
  __shared__ __align__(16) unsigned short Kl[KTILE * DIM];
  __shared__ __align__(16) unsigned short Vt[DIM * KTILE];

  const int qrow = qt * 128 + w * 32 + n;
  const float cs = 0.125f * 1.44269504088896340736f;
  FragU qf[4];
  {
    const float* qp = Q + base + qrow * DIM + h * 8;
#pragma unroll
    for (int ks = 0; ks < 4; ++ks) {
      float4 a = *reinterpret_cast<const float4*>(qp + 16 * ks);
      float4 b = *reinterpret_cast<const float4*>(qp + 16 * ks + 4);
      qf[ks].u[0] = pk2bf(a.x * cs, a.y * cs);
      qf[ks].u[1] = pk2bf(a.z * cs, a.w * cs);
      qf[ks].u[2] = pk2bf(b.x * cs, b.y * cs);
      qf[ks].u[3] = pk2bf(b.z * cs, b.w * cs);
    }
  }

  floatx16 o0, o1;
#pragma unroll
  for (int i = 0; i < 16; ++i) { o0[i] = 0.f; o1[i] = 0.f; }
  float s_run = 0.f;

  for (int kt = 0; kt <= qt; ++kt) {
    __syncthreads();
    {
      const float4* kp4 = reinterpret_cast<const float4*>(K + base + kt * (KTILE * DIM));
      float4 kx[8];
#pragma unroll
      for (int c = 0; c < 8; ++c) kx[c] = kp4[tid + 256 * c];
#pragma unroll
      for (int c = 0; c < 8; ++c) {
        int f4 = tid + 256 * c;
        int kv = f4 >> 4;
        int d0 = (f4 & 15) << 2;
        unsigned lo = pk2bf(kx[c].x, kx[c].y);
        unsigned hi = pk2bf(kx[c].z, kx[c].w);
        unsigned long long u64 = (unsigned long long)lo | ((unsigned long long)hi << 32);
        int idx = (kv << 6) | ((((d0 >> 3) ^ (kv & 7)) << 3) | (d0 & 7));
        *reinterpret_cast<unsigned long long*>(&Kl[idx]) = u64;
      }
      const int s0 = (tid & 63) << 1;
      const int db = (tid >> 6) << 4;
      const int kva = sig23(s0);
      const float* vr0 = V + base + kt * (KTILE * DIM) + kva * DIM + db;
      const float* vr1 = vr0 + DIM;
      float4 va[4], vb[4];
#pragma unroll
      for (int sg = 0; sg < 4; ++sg) {
        va[sg] = *reinterpret_cast<const float4*>(vr0 + 4 * sg);
        vb[sg] = *reinterpret_cast<const float4*>(vr1 + 4 * sg);
      }
      const float* vaf = reinterpret_cast<const float*>(va);
      const float* vbf = reinterpret_cast<const float*>(vb);
#pragma unroll
      for (int j = 0; j < 16; ++j) {
        int d = db + j;
        unsigned u = pk2bf(vaf[j], vbf[j]);
        int idx = (d << 7) | ((((s0 >> 3) ^ (d & 15)) << 3) | (s0 & 7));
        *reinterpret_cast<unsigned*>(&Vt[idx]) = u;
      }
    }
    __syncthreads();

    floatx16 st[4];
#pragma unroll
    for (int tt = 0; tt < 4; ++tt) {
      floatx16 acc;
#pragma unroll
      for (int i = 0; i < 16; ++i) acc[i] = 0.f;
#pragma unroll
      for (int ks = 0; ks < 4; ++ks) {
        const bhalf8 kfrag = *reinterpret_cast<const bhalf8*>(
            &Kl[((32 * tt + n) << 6) | (((2 * ks + h) ^ (n & 7)) << 3)]);
        acc = __builtin_amdgcn_mfma_f32_32x32x16_bf16(kfrag, qf[ks].v, acc, 0, 0, 0);
      }
      st[tt] = acc;
    }

    if (kt == qt) {
#pragma unroll
      for (int tt = 0; tt < 4; ++tt)
#pragma unroll
        for (int r = 0; r < 16; ++r) {
          int kvloc = 32 * tt + (r & 3) + 8 * (r >> 2) + 4 * h;
          st[tt][r] = (kvloc > 32 * w + n) ? -__builtin_inff() : st[tt][r];
        }
    }

    float psum = 0.f;
#pragma unroll
    for (int tt = 0; tt < 4; ++tt)
#pragma unroll
      for (int r = 0; r < 16; ++r) {
        float p = EXP2F(st[tt][r]);
        st[tt][r] = p;
        psum += p;
      }
    psum += __shfl_xor(psum, 32, 64);
    s_run += psum;

#pragma unroll
    for (int tt = 0; tt < 4; ++tt) {
      FragU b0, b1;
      b0.u[0] = pk2bf(st[tt][0],  st[tt][1]);
      b0.u[1] = pk2bf(st[tt][2],  st[tt][3]);
      b0.u[2] = pk2bf(st[tt][4],  st[tt][5]);
      b0.u[3] = pk2bf(st[tt][6],  st[tt][7]);
      b1.u[0] = pk2bf(st[tt][8],  st[tt][9]);
      b1.u[1] = pk2bf(st[tt][10], st[tt][11]);
      b1.u[2] = pk2bf(st[tt][12], st[tt][13]);
      b1.u[3] = pk2bf(st[tt][14], st[tt][15]);

      const int sw = n & 15;
      const bhalf8 v00 = *reinterpret_cast<const bhalf8*>(
          &Vt[(n << 7) | (((4 * tt + 0 + h) ^ sw) << 3)]);
      const bhalf8 v01 = *reinterpret_cast<const bhalf8*>(
          &Vt[(n << 7) | (((4 * tt + 2 + h) ^ sw) << 3)]);
      const bhalf8 v10 = *reinterpret_cast<const bhalf8*>(
          &Vt[((32 + n) << 7) | (((4 * tt + 0 + h) ^ sw) << 3)]);
      const bhalf8 v11 = *reinterpret_cast<const bhalf8*>(
          &Vt[((32 + n) << 7) | (((4 * tt + 2 + h) ^ sw) << 3)]);
      o0 = __builtin_amdgcn_mfma_f32_32x32x16_bf16(v00, b0.v, o0, 0, 0, 0);
      o0 = __builtin_amdgcn_mfma_f32_32x32x16_bf16(v01, b1.v, o0, 0, 0, 0);
      o1 = __builtin_amdgcn_mfma_f32_32x32x16_bf16(v10, b0.v, o1, 0, 0, 0);
      o1 = __builtin_amdgcn_mfma_f32_32x32x16_bf16(v11, b1.v, o1, 0, 0, 0);
    }
  }

  const float inv = 1.0f / s_run;
  float* op = O + base + qrow * DIM;
#pragma unroll
  for (int g = 0; g < 4; ++g) {
    float4 x, y;
    x.x = o0[4 * g] * inv;  x.y = o0[4 * g + 1] * inv;
    x.z = o0[4 * g + 2] * inv;  x.w = o0[4 * g + 3] * inv;
    y.x = o1[4 * g] * inv;  y.y = o1[4 * g + 1] * inv;
    y.z = o1[4 * g + 2] * inv;  y.w = o1[4 * g + 3] * inv;
    *reinterpret_cast<float4*>(op + 8 * g + 4 * h)      = x;
    *reinterpret_cast<float4*>(op + 32 + 8 * g + 4 * h) = y;
  }
}

extern "C" void kernel_launch(void* const* d_in, const int* in_sizes, int n_in,
                              void* d_out, int out_size, void* d_ws, size_t ws_size,
                              hipStream_t stream) {
  (void)in_sizes; (void)n_in; (void)out_size;
  const float* Q = (const float*)d_in[0];
  const float* K = (const float*)d_in[1];
  const float* V = (const float*)d_in[2];
  float* O = (float*)d_out;

  // ws layout (bytes): Kb[16MB] | Vb[16MB]
  const size_t OFF_KB = 0;
  const size_t OFF_VB = 16777216;
  const size_t NEED   = 33554432;

  if (ws_size >= NEED) {
    unsigned short* Kb = (unsigned short*)((char*)d_ws + OFF_KB);
    unsigned short* Vb = (unsigned short*)((char*)d_ws + OFF_VB);
    fa_prep<<<dim3(NBH * NQT), dim3(256), 0, stream>>>(K, V, Kb, Vb);
    fa_main2<<<dim3(NBH * NPAIR), dim3(512), 0, stream>>>(Q, Kb, Vb, O);
  } else {
    fa_mono<<<dim3(NQT * NBH), dim3(256), 0, stream>>>(Q, K, V, O);
  }
}